// Round 2
// baseline (2626.162 us; speedup 1.0000x reference)
//
#include <hip/hip_runtime.h>
#include <hip/hip_bf16.h>

#define NN 50000     // nodes per side (users == items == 50000)
#define NE 600000    // edges per relation
#define HF 256       // hidden features

typedef float f32x4 __attribute__((ext_vector_type(4)));
typedef _Float16 f16x8 __attribute__((ext_vector_type(8)));

// ---------- W[K][256] (fp32) -> Wt[256][K] (fp16) ----------
__global__ __launch_bounds__(256) void k_transpose(const float* __restrict__ W,
                                                   _Float16* __restrict__ Wt, int K) {
  int idx = blockIdx.x * 256 + threadIdx.x;
  if (idx >= K * 256) return;
  int k = idx >> 8;
  int n = idx & 255;
  Wt[(size_t)n * K + k] = (_Float16)W[idx];
}

// ---------- GEMM: Z[M,256] = A[M,K] @ W[K,256], A fp32 -> fp16 on the fly ----------
// block = 256 threads (4 waves); block tile = 64 rows x 256 cols; wave tile = 64x64.
__global__ __launch_bounds__(256) void k_gemm(const float* __restrict__ A,
                                              const _Float16* __restrict__ Wt,
                                              float* __restrict__ Z,
                                              int M, int K) {
  int wave = threadIdx.x >> 6;
  int lane = threadIdx.x & 63;
  int lr = lane & 15;   // fragment row (A) / col (B)
  int kg = lane >> 4;   // k-group: k = kg*8 + j
  int row0 = blockIdx.x * 64;
  int col0 = wave * 64;
  f32x4 acc[4][4];
#pragma unroll
  for (int i = 0; i < 4; ++i)
#pragma unroll
    for (int j = 0; j < 4; ++j) acc[i][j] = (f32x4){0.f, 0.f, 0.f, 0.f};

  for (int k0 = 0; k0 < K; k0 += 32) {
    f16x8 af[4], bfr[4];
#pragma unroll
    for (int mt = 0; mt < 4; ++mt) {
      int r = row0 + mt * 16 + lr;
      if (r >= M) r = M - 1;  // clamp loads; stores are guarded
      const float4* ap = reinterpret_cast<const float4*>(A + (size_t)r * K + k0 + kg * 8);
      float4 a0 = ap[0], a1 = ap[1];
      af[mt] = (f16x8){(_Float16)a0.x, (_Float16)a0.y, (_Float16)a0.z, (_Float16)a0.w,
                       (_Float16)a1.x, (_Float16)a1.y, (_Float16)a1.z, (_Float16)a1.w};
    }
#pragma unroll
    for (int ct = 0; ct < 4; ++ct) {
      int c = col0 + ct * 16 + lr;
      bfr[ct] = *reinterpret_cast<const f16x8*>(Wt + (size_t)c * K + k0 + kg * 8);
    }
#pragma unroll
    for (int mt = 0; mt < 4; ++mt)
#pragma unroll
      for (int ct = 0; ct < 4; ++ct)
        acc[mt][ct] = __builtin_amdgcn_mfma_f32_16x16x32_f16(af[mt], bfr[ct], acc[mt][ct], 0, 0, 0);
  }
  // C/D layout (HW-verified): col = lane&15, row = (lane>>4)*4 + reg
#pragma unroll
  for (int mt = 0; mt < 4; ++mt) {
#pragma unroll
    for (int r = 0; r < 4; ++r) {
      int row = row0 + mt * 16 + kg * 4 + r;
      if (row < M) {
#pragma unroll
        for (int ct = 0; ct < 4; ++ct) {
          int col = col0 + ct * 16 + lr;
          Z[(size_t)row * HF + col] = acc[mt][ct][r];
        }
      }
    }
  }
}

// ---------- el/er: out[n,h] = sum_d Z[n, h*64+d] * av[h*64+d] ----------
__global__ __launch_bounds__(256) void k_attndots(const float* __restrict__ Z,
                                                  const float* __restrict__ av,
                                                  float* __restrict__ out) {
  int t = blockIdx.x * 256 + threadIdx.x;
  if (t >= NN * 4) return;
  int n = t >> 2, h = t & 3;
  const float4* zp = reinterpret_cast<const float4*>(Z + (size_t)n * HF + h * 64);
  const float4* ap = reinterpret_cast<const float4*>(av + h * 64);
  float s = 0.f;
#pragma unroll 4
  for (int i = 0; i < 16; ++i) {
    float4 zv = zp[i];
    float4 a4 = ap[i];
    s += zv.x * a4.x + zv.y * a4.y + zv.z * a4.z + zv.w * a4.w;
  }
  out[t] = s;
}

// ---------- CSR build ----------
__global__ __launch_bounds__(256) void k_hist(const int* __restrict__ dst, int* __restrict__ counts) {
  int e = blockIdx.x * 256 + threadIdx.x;
  if (e < NE) atomicAdd(&counts[dst[e]], 1);
}

__global__ __launch_bounds__(1024) void k_exscan(const int* __restrict__ counts, int* __restrict__ rp) {
  __shared__ int tmp[1024];
  __shared__ int s_carry;
  if (threadIdx.x == 0) s_carry = 0;
  __syncthreads();
  for (int base = 0; base < NN; base += 1024) {
    int i = base + threadIdx.x;
    int v = (i < NN) ? counts[i] : 0;
    tmp[threadIdx.x] = v;
    __syncthreads();
    for (int off = 1; off < 1024; off <<= 1) {
      int t = (threadIdx.x >= off) ? tmp[threadIdx.x - off] : 0;
      __syncthreads();
      tmp[threadIdx.x] += t;
      __syncthreads();
    }
    int carry = s_carry;
    if (i < NN) rp[i] = carry + tmp[threadIdx.x] - v;  // exclusive
    __syncthreads();
    if (threadIdx.x == 0) s_carry = carry + tmp[1023];
    __syncthreads();
  }
  if (threadIdx.x == 0) rp[NN] = s_carry;
}

__global__ __launch_bounds__(256) void k_scatter(const int* __restrict__ src, const int* __restrict__ dst,
                                                 const int* __restrict__ rp, int* __restrict__ fill,
                                                 int* __restrict__ csrc) {
  int e = blockIdx.x * 256 + threadIdx.x;
  if (e < NE) {
    int d = dst[e];
    int pos = rp[d] + atomicAdd(&fill[d], 1);
    csrc[pos] = src[e];
  }
}

// ---------- fused GAT aggregation: one wave per dst node ----------
// lane owns features f0..f0+3 (all in head h = lane>>4). 2-pass segment softmax, no atomics.
__global__ __launch_bounds__(256) void k_aggregate(
    const int* __restrict__ rp, const int* __restrict__ csrc,
    const float* __restrict__ el, const float* __restrict__ er,
    const float* __restrict__ Z, const float* __restrict__ bias,
    float* __restrict__ out) {
  int wid = (blockIdx.x * 256 + threadIdx.x) >> 6;
  if (wid >= NN) return;
  int lane = threadIdx.x & 63;
  int h = lane >> 4;
  int f0 = lane << 2;
  int beg = rp[wid], end = rp[wid + 1];
  float erv = er[wid * 4 + h];
  float m = -INFINITY;
  for (int e = beg; e < end; ++e) {
    int s = csrc[e];
    float x = el[s * 4 + h] + erv;
    x = x >= 0.f ? x : 0.2f * x;
    m = fmaxf(m, x);
  }
  float a0 = 0.f, a1 = 0.f, a2 = 0.f, a3 = 0.f, ssum = 0.f;
  for (int e = beg; e < end; ++e) {
    int s = csrc[e];
    float x = el[s * 4 + h] + erv;
    x = x >= 0.f ? x : 0.2f * x;
    float wgt = __expf(x - m);
    ssum += wgt;
    float4 zv = *reinterpret_cast<const float4*>(Z + (size_t)s * HF + f0);
    a0 += wgt * zv.x;
    a1 += wgt * zv.y;
    a2 += wgt * zv.z;
    a3 += wgt * zv.w;
  }
  float inv = (end > beg) ? (1.0f / ssum) : 0.f;
  float4 bv = *reinterpret_cast<const float4*>(bias + f0);
  float4 r;
  r.x = a0 * inv + bv.x;
  r.y = a1 * inv + bv.y;
  r.z = a2 * inv + bv.z;
  r.w = a3 * inv + bv.w;
  *reinterpret_cast<float4*>(out + (size_t)wid * HF + f0) = r;
}

// ---------- batchnorm ----------
__global__ __launch_bounds__(256) void k_bn_stats(const float* __restrict__ X,
                                                  float* __restrict__ sums, float* __restrict__ sqs) {
  int c = threadIdx.x;
  float s = 0.f, q = 0.f;
  for (int r = blockIdx.x; r < NN; r += gridDim.x) {
    float v = X[(size_t)r * HF + c];
    s += v;
    q += v * v;
  }
  atomicAdd(&sums[c], s);
  atomicAdd(&sqs[c], q);
}

__global__ __launch_bounds__(256) void k_bn_apply(const float* __restrict__ X,
    const float* __restrict__ sums, const float* __restrict__ sqs,
    const float* __restrict__ g, const float* __restrict__ bt,
    float* __restrict__ Y, int act) {
  int idx = blockIdx.x * 256 + threadIdx.x;  // grid = NN blocks -> exactly NN*256 elems
  int c = idx & 255;
  const float invN = 1.0f / NN;
  float mu = sums[c] * invN;
  float var = sqs[c] * invN - mu * mu;
  float sc = rsqrtf(var + 1e-5f) * g[c];
  float v = (X[idx] - mu) * sc + bt[c];
  v = act ? tanhf(v) : (v >= 0.f ? v : 0.01f * v);
  Y[idx] = v;
}

extern "C" void kernel_launch(void* const* d_in, const int* in_sizes, int n_in,
                              void* d_out, int out_size, void* d_ws, size_t ws_size,
                              hipStream_t stream) {
  (void)in_sizes; (void)n_in; (void)out_size; (void)ws_size;
  const float* x_user = (const float*)d_in[0];
  const float* x_item = (const float*)d_in[1];
  const int* ui_src = (const int*)d_in[2];
  const int* ui_dst = (const int*)d_in[3];
  const int* iu_src = (const int*)d_in[4];
  const int* iu_dst = (const int*)d_in[5];
  const float *Wp[4], *alp[4], *arp[4], *bp[4];
  for (int l = 0; l < 4; ++l) {
    Wp[l]  = (const float*)d_in[6 + 4 * l];
    alp[l] = (const float*)d_in[7 + 4 * l];
    arp[l] = (const float*)d_in[8 + 4 * l];
    bp[l]  = (const float*)d_in[9 + 4 * l];
  }
  const float* bng = (const float*)d_in[22];
  const float* bnb = (const float*)d_in[23];

  char* w = (char*)d_ws;
  auto alloc = [&](size_t bytes) -> void* {
    void* p = (void*)w;
    w += (bytes + 255) & ~(size_t)255;
    return p;
  };
  float* HU = (float*)alloc((size_t)NN * HF * 4);
  float* HI = (float*)alloc((size_t)NN * HF * 4);
  float* ZA = (float*)alloc((size_t)NN * HF * 4);
  float* ZB = (float*)alloc((size_t)NN * HF * 4);
  float* RAWU = (float*)alloc((size_t)NN * HF * 4);
  float* RAWI = (float*)alloc((size_t)NN * HF * 4);
  float* EL = (float*)alloc((size_t)NN * 4 * 4);
  float* ER = (float*)alloc((size_t)NN * 4 * 4);
  _Float16* WT = (_Float16*)alloc((size_t)8 * 65536 * 2);
  int* rp_ui = (int*)alloc((size_t)(NN + 1) * 4);
  int* rp_iu = (int*)alloc((size_t)(NN + 1) * 4);
  int* csrc_ui = (int*)alloc((size_t)NE * 4);
  int* csrc_iu = (int*)alloc((size_t)NE * 4);
  int* counts = (int*)alloc((size_t)4 * NN * 4);  // counts_ui | counts_iu | fill_ui | fill_iu
  float* stats = (float*)alloc((size_t)6 * 512 * 4);

  int* counts_ui = counts;
  int* counts_iu = counts + NN;
  int* fill_ui = counts + 2 * NN;
  int* fill_iu = counts + 3 * NN;

  hipMemsetAsync(counts, 0, (size_t)4 * NN * 4, stream);
  hipMemsetAsync(stats, 0, (size_t)6 * 512 * 4, stream);

  // weight transposes + fp16 conversion (once per call)
  for (int l = 0; l < 4; ++l) {
    int K = (l == 0) ? 128 : 256;
    for (int r = 0; r < 2; ++r)
      k_transpose<<<K, 256, 0, stream>>>(Wp[l] + (size_t)r * K * HF, WT + (size_t)(l * 2 + r) * 65536, K);
  }
  // CSR builds (edges shared by all layers)
  int egrid = (NE + 255) / 256;
  k_hist<<<egrid, 256, 0, stream>>>(ui_dst, counts_ui);
  k_hist<<<egrid, 256, 0, stream>>>(iu_dst, counts_iu);
  k_exscan<<<1, 1024, 0, stream>>>(counts_ui, rp_ui);
  k_exscan<<<1, 1024, 0, stream>>>(counts_iu, rp_iu);
  k_scatter<<<egrid, 256, 0, stream>>>(ui_src, ui_dst, rp_ui, fill_ui, csrc_ui);
  k_scatter<<<egrid, 256, 0, stream>>>(iu_src, iu_dst, rp_iu, fill_iu, csrc_iu);

  const float* hu = x_user;
  const float* hi = x_item;
  int mgrid = (NN + 63) / 64;
  int dgrid = (NN * 4 + 255) / 256;
  int agrid = (NN + 3) / 4;
  float* out_user = (float*)d_out;
  float* out_item = (float*)d_out + (size_t)NN * HF;

  for (int l = 0; l < 4; ++l) {
    int K = (l == 0) ? 128 : 256;
    const _Float16* W0t = WT + (size_t)(l * 2 + 0) * 65536;
    const _Float16* W1t = WT + (size_t)(l * 2 + 1) * 65536;

    // relation u->i (dst = items): z_src = hu@W0, z_dst = hi@W0
    k_gemm<<<mgrid, 256, 0, stream>>>(hu, W0t, ZA, NN, K);
    k_gemm<<<mgrid, 256, 0, stream>>>(hi, W0t, ZB, NN, K);
    k_attndots<<<dgrid, 256, 0, stream>>>(ZA, alp[l] + 0, EL);
    k_attndots<<<dgrid, 256, 0, stream>>>(ZB, arp[l] + 0, ER);
    k_aggregate<<<agrid, 256, 0, stream>>>(rp_ui, csrc_ui, EL, ER, ZA, bp[l] + 0,
                                           (l < 3) ? RAWI : out_item);

    // relation i->u (dst = users): z_src = hi@W1, z_dst = hu@W1
    k_gemm<<<mgrid, 256, 0, stream>>>(hi, W1t, ZA, NN, K);
    k_gemm<<<mgrid, 256, 0, stream>>>(hu, W1t, ZB, NN, K);
    k_attndots<<<dgrid, 256, 0, stream>>>(ZA, alp[l] + 256, EL);
    k_attndots<<<dgrid, 256, 0, stream>>>(ZB, arp[l] + 256, ER);
    k_aggregate<<<agrid, 256, 0, stream>>>(rp_iu, csrc_iu, EL, ER, ZA, bp[l] + 256,
                                           (l < 3) ? RAWU : out_user);

    if (l < 3) {
      int act = (l == 2) ? 1 : 0;
      float* su = stats + (size_t)(l * 2 + 0) * 512;
      float* qu = su + 256;
      float* si = stats + (size_t)(l * 2 + 1) * 512;
      float* qi = si + 256;
      k_bn_stats<<<512, 256, 0, stream>>>(RAWU, su, qu);
      k_bn_stats<<<512, 256, 0, stream>>>(RAWI, si, qi);
      k_bn_apply<<<NN, 256, 0, stream>>>(RAWU, su, qu, bng + (size_t)(l * 2 + 0) * 256,
                                         bnb + (size_t)(l * 2 + 0) * 256, HU, act);
      k_bn_apply<<<NN, 256, 0, stream>>>(RAWI, si, qi, bng + (size_t)(l * 2 + 1) * 256,
                                         bnb + (size_t)(l * 2 + 1) * 256, HI, act);
      hu = HU;
      hi = HI;
    }
  }
}

// Round 3
// 1960.405 us; speedup vs baseline: 1.3396x; 1.3396x over previous
//
#include <hip/hip_runtime.h>
#include <hip/hip_bf16.h>

#define NN 50000     // nodes per side (users == items == 50000)
#define NE 600000    // edges per relation
#define HF 256       // hidden features

typedef float f32x4 __attribute__((ext_vector_type(4)));
typedef _Float16 f16x8 __attribute__((ext_vector_type(8)));
typedef _Float16 f16x4 __attribute__((ext_vector_type(4)));

// ---------- W[K][256] (fp32) -> Wt[256][K] (fp16) ----------
__global__ __launch_bounds__(256) void k_transpose(const float* __restrict__ W,
                                                   _Float16* __restrict__ Wt, int K) {
  int idx = blockIdx.x * 256 + threadIdx.x;
  if (idx >= K * 256) return;
  int k = idx >> 8;
  int n = idx & 255;
  Wt[(size_t)n * K + k] = (_Float16)W[idx];
}

// ---------- attn projections: out[combo][k][h] = sum_d W[combo>>1][k, h*64+d] * a[h*64+d] ----------
// combo: 0 = W0 . al0, 1 = W0 . ar0, 2 = W1 . al1, 3 = W1 . ar1
__global__ __launch_bounds__(256) void k_makeattn(const float* __restrict__ Wfull,  // [2,K,256]
                                                  const float* __restrict__ al,    // [2,256]
                                                  const float* __restrict__ ar,    // [2,256]
                                                  int K, float* __restrict__ out) {
  int idx = blockIdx.x * 256 + threadIdx.x;
  if (idx >= 4 * K * 4) return;
  int h = idx & 3;
  int k = (idx >> 2) % K;
  int combo = idx / (4 * K);
  const float* W = Wfull + (size_t)(combo >> 1) * K * 256;
  const float* a = ((combo & 1) ? ar : al) + (combo >> 1) * 256 + h * 64;
  const float* wrow = W + (size_t)k * 256 + h * 64;
  float s = 0.f;
#pragma unroll 8
  for (int d = 0; d < 64; ++d) s += wrow[d] * a[d];
  out[(size_t)combo * K * 4 + k * 4 + h] = s;
}

// ---------- dual GEMV: one wave per row; outA[n,h]=X[n,:].wa[:,h], outB likewise ----------
__global__ __launch_bounds__(256) void k_gemv4(const float* __restrict__ X,
                                               const float* __restrict__ wa,  // [K][4]
                                               const float* __restrict__ wb,  // [K][4]
                                               float* __restrict__ outA, float* __restrict__ outB,
                                               int K) {
  int wid = (blockIdx.x * 256 + threadIdx.x) >> 6;
  if (wid >= NN) return;
  int lane = threadIdx.x & 63;
  float pa0 = 0.f, pa1 = 0.f, pa2 = 0.f, pa3 = 0.f;
  float pb0 = 0.f, pb1 = 0.f, pb2 = 0.f, pb3 = 0.f;
  int k0 = lane * 4;
  if (k0 < K) {
    float4 x = *reinterpret_cast<const float4*>(X + (size_t)wid * K + k0);
    float xv[4] = {x.x, x.y, x.z, x.w};
#pragma unroll
    for (int j = 0; j < 4; ++j) {
      float4 wav = *reinterpret_cast<const float4*>(wa + (k0 + j) * 4);
      float4 wbv = *reinterpret_cast<const float4*>(wb + (k0 + j) * 4);
      pa0 += xv[j] * wav.x; pa1 += xv[j] * wav.y; pa2 += xv[j] * wav.z; pa3 += xv[j] * wav.w;
      pb0 += xv[j] * wbv.x; pb1 += xv[j] * wbv.y; pb2 += xv[j] * wbv.z; pb3 += xv[j] * wbv.w;
    }
  }
#pragma unroll
  for (int off = 32; off > 0; off >>= 1) {
    pa0 += __shfl_down(pa0, off); pa1 += __shfl_down(pa1, off);
    pa2 += __shfl_down(pa2, off); pa3 += __shfl_down(pa3, off);
    pb0 += __shfl_down(pb0, off); pb1 += __shfl_down(pb1, off);
    pb2 += __shfl_down(pb2, off); pb3 += __shfl_down(pb3, off);
  }
  if (lane == 0) {
    float4* oa = reinterpret_cast<float4*>(outA + (size_t)wid * 4);
    float4* ob = reinterpret_cast<float4*>(outB + (size_t)wid * 4);
    *oa = (float4){pa0, pa1, pa2, pa3};
    *ob = (float4){pb0, pb1, pb2, pb3};
  }
}

// ---------- GEMM: Z[M,256](fp16) = A[M,K](fp32) @ W[K,256], fragments fp16 ----------
__global__ __launch_bounds__(256) void k_gemm(const float* __restrict__ A,
                                              const _Float16* __restrict__ Wt,
                                              _Float16* __restrict__ Z,
                                              int M, int K) {
  int wave = threadIdx.x >> 6;
  int lane = threadIdx.x & 63;
  int lr = lane & 15;   // fragment row (A) / col (B)
  int kg = lane >> 4;   // k-group: k = kg*8 + j
  int row0 = blockIdx.x * 64;
  int col0 = wave * 64;
  f32x4 acc[4][4];
#pragma unroll
  for (int i = 0; i < 4; ++i)
#pragma unroll
    for (int j = 0; j < 4; ++j) acc[i][j] = (f32x4){0.f, 0.f, 0.f, 0.f};

  for (int k0 = 0; k0 < K; k0 += 32) {
    f16x8 af[4], bfr[4];
#pragma unroll
    for (int mt = 0; mt < 4; ++mt) {
      int r = row0 + mt * 16 + lr;
      if (r >= M) r = M - 1;  // clamp loads; stores are guarded
      const float4* ap = reinterpret_cast<const float4*>(A + (size_t)r * K + k0 + kg * 8);
      float4 a0 = ap[0], a1 = ap[1];
      af[mt] = (f16x8){(_Float16)a0.x, (_Float16)a0.y, (_Float16)a0.z, (_Float16)a0.w,
                       (_Float16)a1.x, (_Float16)a1.y, (_Float16)a1.z, (_Float16)a1.w};
    }
#pragma unroll
    for (int ct = 0; ct < 4; ++ct) {
      int c = col0 + ct * 16 + lr;
      bfr[ct] = *reinterpret_cast<const f16x8*>(Wt + (size_t)c * K + k0 + kg * 8);
    }
#pragma unroll
    for (int mt = 0; mt < 4; ++mt)
#pragma unroll
      for (int ct = 0; ct < 4; ++ct)
        acc[mt][ct] = __builtin_amdgcn_mfma_f32_16x16x32_f16(af[mt], bfr[ct], acc[mt][ct], 0, 0, 0);
  }
  // C/D layout: col = lane&15, row = (lane>>4)*4 + reg
#pragma unroll
  for (int mt = 0; mt < 4; ++mt) {
#pragma unroll
    for (int r = 0; r < 4; ++r) {
      int row = row0 + mt * 16 + kg * 4 + r;
      if (row < M) {
#pragma unroll
        for (int ct = 0; ct < 4; ++ct) {
          int col = col0 + ct * 16 + lr;
          Z[(size_t)row * HF + col] = (_Float16)acc[mt][ct][r];
        }
      }
    }
  }
}

// ---------- CSR build ----------
__global__ __launch_bounds__(256) void k_hist(const int* __restrict__ dst, int* __restrict__ counts) {
  int e = blockIdx.x * 256 + threadIdx.x;
  if (e < NE) atomicAdd(&counts[dst[e]], 1);
}

__global__ __launch_bounds__(1024) void k_scan1(const int* __restrict__ counts,
                                                int* __restrict__ rp, int* __restrict__ bsum) {
  __shared__ int tmp[1024];
  int i = blockIdx.x * 1024 + threadIdx.x;
  int v = (i < NN) ? counts[i] : 0;
  tmp[threadIdx.x] = v;
  __syncthreads();
  for (int off = 1; off < 1024; off <<= 1) {
    int t = (threadIdx.x >= off) ? tmp[threadIdx.x - off] : 0;
    __syncthreads();
    tmp[threadIdx.x] += t;
    __syncthreads();
  }
  if (i < NN) rp[i] = tmp[threadIdx.x] - v;  // block-local exclusive
  if (threadIdx.x == 1023) bsum[blockIdx.x] = tmp[1023];
}

__global__ __launch_bounds__(64) void k_scan2(int* __restrict__ bsum, int nb) {
  int l = threadIdx.x;
  int orig = (l < nb) ? bsum[l] : 0;
  int v = orig;
#pragma unroll
  for (int off = 1; off < 64; off <<= 1) {
    int t = __shfl_up(v, off);
    if (l >= off) v += t;
  }
  if (l < nb) bsum[l] = v - orig;  // exclusive
}

__global__ __launch_bounds__(1024) void k_scan3(int* __restrict__ rp, const int* __restrict__ bsum) {
  int i = blockIdx.x * 1024 + threadIdx.x;
  if (i < NN) rp[i] += bsum[blockIdx.x];
  if (i == 0) rp[NN] = NE;
}

__global__ __launch_bounds__(256) void k_scatter(const int* __restrict__ src, const int* __restrict__ dst,
                                                 const int* __restrict__ rp, int* __restrict__ fill,
                                                 int* __restrict__ csrc) {
  int e = blockIdx.x * 256 + threadIdx.x;
  if (e < NE) {
    int d = dst[e];
    int pos = rp[d] + atomicAdd(&fill[d], 1);
    csrc[pos] = src[e];
  }
}

// ---------- fused GAT aggregation: one wave per dst node, Z in fp16 ----------
__global__ __launch_bounds__(256) void k_aggregate(
    const int* __restrict__ rp, const int* __restrict__ csrc,
    const float* __restrict__ el, const float* __restrict__ er,
    const _Float16* __restrict__ Z, const float* __restrict__ bias,
    float* __restrict__ out) {
  int wid = (blockIdx.x * 256 + threadIdx.x) >> 6;
  if (wid >= NN) return;
  int lane = threadIdx.x & 63;
  int h = lane >> 4;
  int f0 = lane << 2;
  int beg = rp[wid], end = rp[wid + 1];
  float erv = er[wid * 4 + h];
  float m = -INFINITY;
  for (int e = beg; e < end; ++e) {
    int s = csrc[e];
    float x = el[s * 4 + h] + erv;
    x = x >= 0.f ? x : 0.2f * x;
    m = fmaxf(m, x);
  }
  float a0 = 0.f, a1 = 0.f, a2 = 0.f, a3 = 0.f, ssum = 0.f;
  for (int e = beg; e < end; ++e) {
    int s = csrc[e];
    float x = el[s * 4 + h] + erv;
    x = x >= 0.f ? x : 0.2f * x;
    float wgt = __expf(x - m);
    ssum += wgt;
    f16x4 zv = *reinterpret_cast<const f16x4*>(Z + (size_t)s * HF + f0);
    a0 += wgt * (float)zv.x;
    a1 += wgt * (float)zv.y;
    a2 += wgt * (float)zv.z;
    a3 += wgt * (float)zv.w;
  }
  float inv = (end > beg) ? (1.0f / ssum) : 0.f;
  float4 bv = *reinterpret_cast<const float4*>(bias + f0);
  float4 r;
  r.x = a0 * inv + bv.x;
  r.y = a1 * inv + bv.y;
  r.z = a2 * inv + bv.z;
  r.w = a3 * inv + bv.w;
  *reinterpret_cast<float4*>(out + (size_t)wid * HF + f0) = r;
}

// ---------- batchnorm ----------
__global__ __launch_bounds__(256) void k_bn_stats(const float* __restrict__ X,
                                                  float* __restrict__ sums, float* __restrict__ sqs) {
  int c = threadIdx.x;
  float s = 0.f, q = 0.f;
  for (int r = blockIdx.x; r < NN; r += gridDim.x) {
    float v = X[(size_t)r * HF + c];
    s += v;
    q += v * v;
  }
  atomicAdd(&sums[c], s);
  atomicAdd(&sqs[c], q);
}

__global__ __launch_bounds__(256) void k_bn_apply(const float* __restrict__ X,
    const float* __restrict__ sums, const float* __restrict__ sqs,
    const float* __restrict__ g, const float* __restrict__ bt,
    float* __restrict__ Y, int act) {
  int idx = blockIdx.x * 256 + threadIdx.x;  // grid = NN blocks -> exactly NN*256 elems
  int c = idx & 255;
  const float invN = 1.0f / NN;
  float mu = sums[c] * invN;
  float var = sqs[c] * invN - mu * mu;
  float sc = rsqrtf(var + 1e-5f) * g[c];
  float v = (X[idx] - mu) * sc + bt[c];
  v = act ? tanhf(v) : (v >= 0.f ? v : 0.01f * v);
  Y[idx] = v;
}

extern "C" void kernel_launch(void* const* d_in, const int* in_sizes, int n_in,
                              void* d_out, int out_size, void* d_ws, size_t ws_size,
                              hipStream_t stream) {
  (void)in_sizes; (void)n_in; (void)out_size; (void)ws_size;
  const float* x_user = (const float*)d_in[0];
  const float* x_item = (const float*)d_in[1];
  const int* ui_src = (const int*)d_in[2];
  const int* ui_dst = (const int*)d_in[3];
  const int* iu_src = (const int*)d_in[4];
  const int* iu_dst = (const int*)d_in[5];
  const float *Wp[4], *alp[4], *arp[4], *bp[4];
  for (int l = 0; l < 4; ++l) {
    Wp[l]  = (const float*)d_in[6 + 4 * l];
    alp[l] = (const float*)d_in[7 + 4 * l];
    arp[l] = (const float*)d_in[8 + 4 * l];
    bp[l]  = (const float*)d_in[9 + 4 * l];
  }
  const float* bng = (const float*)d_in[22];
  const float* bnb = (const float*)d_in[23];

  char* w = (char*)d_ws;
  auto alloc = [&](size_t bytes) -> void* {
    void* p = (void*)w;
    w += (bytes + 255) & ~(size_t)255;
    return p;
  };
  float* HU = (float*)alloc((size_t)NN * HF * 4);
  float* HI = (float*)alloc((size_t)NN * HF * 4);
  _Float16* Z = (_Float16*)alloc((size_t)NN * HF * 2);
  float* RAWU = (float*)alloc((size_t)NN * HF * 4);
  float* RAWI = (float*)alloc((size_t)NN * HF * 4);
  float* EL0 = (float*)alloc((size_t)NN * 4 * 4);
  float* ER0 = (float*)alloc((size_t)NN * 4 * 4);
  float* EL1 = (float*)alloc((size_t)NN * 4 * 4);
  float* ER1 = (float*)alloc((size_t)NN * 4 * 4);
  _Float16* WT = (_Float16*)alloc((size_t)8 * 65536 * 2);
  float* ATTN = (float*)alloc((size_t)4 * 256 * 4 * 4);  // 4 combos x K x 4 heads (K<=256)
  int* rp_ui = (int*)alloc((size_t)(NN + 1) * 4);
  int* rp_iu = (int*)alloc((size_t)(NN + 1) * 4);
  int* csrc_ui = (int*)alloc((size_t)NE * 4);
  int* csrc_iu = (int*)alloc((size_t)NE * 4);
  int* counts = (int*)alloc((size_t)4 * NN * 4);  // counts_ui | counts_iu | fill_ui | fill_iu
  int* bsum_ui = (int*)alloc((size_t)64 * 4);
  int* bsum_iu = (int*)alloc((size_t)64 * 4);
  float* stats = (float*)alloc((size_t)6 * 512 * 4);

  int* counts_ui = counts;
  int* counts_iu = counts + NN;
  int* fill_ui = counts + 2 * NN;
  int* fill_iu = counts + 3 * NN;

  hipMemsetAsync(counts, 0, (size_t)4 * NN * 4, stream);
  hipMemsetAsync(stats, 0, (size_t)6 * 512 * 4, stream);

  // weight transposes + fp16 conversion (once per call)
  for (int l = 0; l < 4; ++l) {
    int K = (l == 0) ? 128 : 256;
    for (int r = 0; r < 2; ++r)
      k_transpose<<<K, 256, 0, stream>>>(Wp[l] + (size_t)r * K * HF, WT + (size_t)(l * 2 + r) * 65536, K);
  }
  // CSR builds (edges shared by all layers)
  int egrid = (NE + 255) / 256;
  int nscan = (NN + 1023) / 1024;
  k_hist<<<egrid, 256, 0, stream>>>(ui_dst, counts_ui);
  k_hist<<<egrid, 256, 0, stream>>>(iu_dst, counts_iu);
  k_scan1<<<nscan, 1024, 0, stream>>>(counts_ui, rp_ui, bsum_ui);
  k_scan2<<<1, 64, 0, stream>>>(bsum_ui, nscan);
  k_scan3<<<nscan, 1024, 0, stream>>>(rp_ui, bsum_ui);
  k_scan1<<<nscan, 1024, 0, stream>>>(counts_iu, rp_iu, bsum_iu);
  k_scan2<<<1, 64, 0, stream>>>(bsum_iu, nscan);
  k_scan3<<<nscan, 1024, 0, stream>>>(rp_iu, bsum_iu);
  k_scatter<<<egrid, 256, 0, stream>>>(ui_src, ui_dst, rp_ui, fill_ui, csrc_ui);
  k_scatter<<<egrid, 256, 0, stream>>>(iu_src, iu_dst, rp_iu, fill_iu, csrc_iu);

  const float* hu = x_user;
  const float* hi = x_item;
  int mgrid = (NN + 63) / 64;
  int agrid = (NN + 3) / 4;
  float* out_user = (float*)d_out;
  float* out_item = (float*)d_out + (size_t)NN * HF;

  for (int l = 0; l < 4; ++l) {
    int K = (l == 0) ? 128 : 256;
    const _Float16* W0t = WT + (size_t)(l * 2 + 0) * 65536;
    const _Float16* W1t = WT + (size_t)(l * 2 + 1) * 65536;

    // attn projection tables: wal0 | war0 | wal1 | war1, each [K][4]
    k_makeattn<<<(4 * K * 4 + 255) / 256, 256, 0, stream>>>(Wp[l], alp[l], arp[l], K, ATTN);
    // el/er via x @ (W.a): hu -> el_ui (wal0), er_iu (war1); hi -> er_ui (war0), el_iu (wal1)
    k_gemv4<<<agrid, 256, 0, stream>>>(hu, ATTN + 0 * K * 4, ATTN + 3 * K * 4, EL0, ER1, K);
    k_gemv4<<<agrid, 256, 0, stream>>>(hi, ATTN + 1 * K * 4, ATTN + 2 * K * 4, ER0, EL1, K);

    // relation u->i (dst = items): z_src = hu@W0
    k_gemm<<<mgrid, 256, 0, stream>>>(hu, W0t, Z, NN, K);
    k_aggregate<<<agrid, 256, 0, stream>>>(rp_ui, csrc_ui, EL0, ER0, Z, bp[l] + 0,
                                           (l < 3) ? RAWI : out_item);

    // relation i->u (dst = users): z_src = hi@W1
    k_gemm<<<mgrid, 256, 0, stream>>>(hi, W1t, Z, NN, K);
    k_aggregate<<<agrid, 256, 0, stream>>>(rp_iu, csrc_iu, EL1, ER1, Z, bp[l] + 256,
                                           (l < 3) ? RAWU : out_user);

    if (l < 3) {
      int act = (l == 2) ? 1 : 0;
      float* su = stats + (size_t)(l * 2 + 0) * 512;
      float* qu = su + 256;
      float* si = stats + (size_t)(l * 2 + 1) * 512;
      float* qi = si + 256;
      k_bn_stats<<<512, 256, 0, stream>>>(RAWU, su, qu);
      k_bn_stats<<<512, 256, 0, stream>>>(RAWI, si, qi);
      k_bn_apply<<<NN, 256, 0, stream>>>(RAWU, su, qu, bng + (size_t)(l * 2 + 0) * 256,
                                         bnb + (size_t)(l * 2 + 0) * 256, HU, act);
      k_bn_apply<<<NN, 256, 0, stream>>>(RAWI, si, qi, bng + (size_t)(l * 2 + 1) * 256,
                                         bnb + (size_t)(l * 2 + 1) * 256, HI, act);
      hu = HU;
      hi = HI;
    }
  }
}